// Round 7
// baseline (290.318 us; speedup 1.0000x reference)
//
#include <hip/hip_runtime.h>
#include <hip/hip_bf16.h>

#define NN 10000
#define EE 320000
#define ET (EE + NN)      // 330000 edges incl self-loops
#define FIN 256
#define HD 128
#define NEG 0.2f

// Inputs fp32, edge_index int32, OUTPUT fp32.

// ---------------- CSR build (counting sort by dst) ----------------

__global__ void k_hist(const int* __restrict__ ei, int* __restrict__ counts) {
    int i = blockIdx.x * blockDim.x + threadIdx.x;
    if (i >= ET) return;
    int d = (i < EE) ? ei[EE + i] : (i - EE);
    atomicAdd(&counts[d], 1);
}

// single 256-thread block: exclusive scan counts[NN] -> offsets[NN+1], cursor[NN]
__global__ void k_scan(const int* __restrict__ counts,
                       int* __restrict__ offsets,
                       int* __restrict__ cursor) {
    const int CHUNK = 40;   // 256*40 = 10240 >= 10000
    __shared__ int sums[256];
    int t = threadIdx.x;
    int base = t * CHUNK;
    int s = 0;
    for (int i = 0; i < CHUNK; i++) {
        int idx = base + i;
        if (idx < NN) s += counts[idx];
    }
    sums[t] = s;
    __syncthreads();
    for (int off = 1; off < 256; off <<= 1) {
        int v = (t >= off) ? sums[t - off] : 0;
        __syncthreads();
        sums[t] += v;
        __syncthreads();
    }
    int run = (t > 0) ? sums[t - 1] : 0;
    for (int i = 0; i < CHUNK; i++) {
        int idx = base + i;
        if (idx < NN) {
            offsets[idx] = run;
            cursor[idx]  = run;
            run += counts[idx];
        }
    }
    if (t == 255) offsets[NN] = sums[255];
}

// scatter stores the SOURCE node id at the CSR position
__global__ void k_scatter(const int* __restrict__ ei, int* __restrict__ cursor,
                          int* __restrict__ srclist) {
    int i = blockIdx.x * blockDim.x + threadIdx.x;
    if (i >= ET) return;
    int s, d;
    if (i < EE) { s = ei[i]; d = ei[EE + i]; }
    else        { s = i - EE; d = s; }
    int pos = atomicAdd(&cursor[d], 1);
    srclist[pos] = s;
}

// ---------------- GEMM layer 1: h = x @ W1 (K=256), no LDS ----------------
// 128 threads (thread = feature), 16 nodes/block. x addresses are wave-uniform
// (scalar-load path); W loads coalesced VMEM. One x float4 feeds 4 FMAs with
// zero LDS-pipe use.

__global__ void k_gemm1(const float* __restrict__ x,
                        const float* __restrict__ W,
                        const float* __restrict__ atts,
                        const float* __restrict__ attd,
                        float* __restrict__ h,
                        float* __restrict__ a_s,
                        float* __restrict__ a_d) {
    int t = threadIdx.x;
    int m0 = blockIdx.x * 16;       // 625 blocks
    const float* xb = x + (size_t)m0 * FIN;
    float acc[16];
    #pragma unroll
    for (int m = 0; m < 16; m++) acc[m] = 0.f;

    for (int k = 0; k < FIN; k += 4) {
        float w0 = W[(k + 0) * HD + t];
        float w1 = W[(k + 1) * HD + t];
        float w2 = W[(k + 2) * HD + t];
        float w3 = W[(k + 3) * HD + t];
        #pragma unroll
        for (int m = 0; m < 16; m++) {
            float4 xk = *(const float4*)(xb + (size_t)m * FIN + k);
            acc[m] += xk.x * w0 + xk.y * w1 + xk.z * w2 + xk.w * w3;
        }
    }

    float ats = atts[t], atd = attd[t];
    __shared__ float ps[2][2][16];
    int wv = t >> 6, ln = t & 63;
    #pragma unroll
    for (int m = 0; m < 16; m++) {
        h[(size_t)(m0 + m) * HD + t] = acc[m];
        float vs = acc[m] * ats, vd = acc[m] * atd;
        #pragma unroll
        for (int off = 32; off > 0; off >>= 1) {
            vs += __shfl_down(vs, off);
            vd += __shfl_down(vd, off);
        }
        if (ln == 0) { ps[0][wv][m] = vs; ps[1][wv][m] = vd; }
    }
    __syncthreads();
    if (t < 16) a_s[m0 + t] = ps[0][0][t] + ps[0][1][t];
    else if (t < 32) a_d[m0 + t - 16] = ps[1][0][t - 16] + ps[1][1][t - 16];
}

// ---------------- GEMM layer 2: h = g1 @ W2 (K=128), same structure ----------------

__global__ void k_gemm2(const float* __restrict__ x,
                        const float* __restrict__ W,
                        const float* __restrict__ atts,
                        const float* __restrict__ attd,
                        float* __restrict__ h,
                        float* __restrict__ a_s,
                        float* __restrict__ a_d) {
    int t = threadIdx.x;
    int m0 = blockIdx.x * 16;
    const float* xb = x + (size_t)m0 * HD;
    float acc[16];
    #pragma unroll
    for (int m = 0; m < 16; m++) acc[m] = 0.f;

    for (int k = 0; k < HD; k += 4) {
        float w0 = W[(k + 0) * HD + t];
        float w1 = W[(k + 1) * HD + t];
        float w2 = W[(k + 2) * HD + t];
        float w3 = W[(k + 3) * HD + t];
        #pragma unroll
        for (int m = 0; m < 16; m++) {
            float4 xk = *(const float4*)(xb + (size_t)m * HD + k);
            acc[m] += xk.x * w0 + xk.y * w1 + xk.z * w2 + xk.w * w3;
        }
    }

    float ats = atts[t], atd = attd[t];
    __shared__ float ps[2][2][16];
    int wv = t >> 6, ln = t & 63;
    #pragma unroll
    for (int m = 0; m < 16; m++) {
        h[(size_t)(m0 + m) * HD + t] = acc[m];
        float vs = acc[m] * ats, vd = acc[m] * atd;
        #pragma unroll
        for (int off = 32; off > 0; off >>= 1) {
            vs += __shfl_down(vs, off);
            vd += __shfl_down(vd, off);
        }
        if (ln == 0) { ps[0][wv][m] = vs; ps[1][wv][m] = vd; }
    }
    __syncthreads();
    if (t < 16) a_s[m0 + t] = ps[0][0][t] + ps[0][1][t];
    else if (t < 32) a_d[m0 + t - 16] = ps[1][0][t - 16] + ps[1][1][t - 16];
}

// ---------------- aggregation: one WAVE per dst node, lane owns float2 ----------
// All 64 lanes share each edge: z identical across lanes (no reduction, no LDS,
// no __syncthreads). 4-deep edge unroll = 4 independent gather chains in flight.
// exp fused (max-subtraction skipped: shift-invariant, e is O(1)).
// z > 0 structurally (self-loop per node).

__device__ __forceinline__ float edge_w(float as_v, float adn) {
    float e = as_v + adn;
    e = (e > 0.f) ? e : NEG * e;
    return __expf(e);
}

__global__ void k_agg1(const int* __restrict__ offsets,
                       const int* __restrict__ srclist,
                       const float* __restrict__ a_s,
                       const float* __restrict__ a_d,
                       const float2* __restrict__ h2,
                       const float* __restrict__ bias,
                       float* __restrict__ g) {
    int node = blockIdx.x * 4 + (threadIdx.x >> 6);   // 2500 blocks x 4 waves
    int l = threadIdx.x & 63;
    int beg = offsets[node], end = offsets[node + 1];
    float adn = a_d[node];
    float ax = 0.f, ay = 0.f, z = 0.f;
    int p = beg;
    for (; p + 4 <= end; p += 4) {
        int s0 = srclist[p], s1 = srclist[p + 1], s2 = srclist[p + 2], s3 = srclist[p + 3];
        float2 h0 = h2[(size_t)s0 * 64 + l];
        float2 h1 = h2[(size_t)s1 * 64 + l];
        float2 hv2 = h2[(size_t)s2 * 64 + l];
        float2 h3 = h2[(size_t)s3 * 64 + l];
        float w0 = edge_w(a_s[s0], adn);
        float w1 = edge_w(a_s[s1], adn);
        float w2 = edge_w(a_s[s2], adn);
        float w3 = edge_w(a_s[s3], adn);
        z += (w0 + w1) + (w2 + w3);
        ax += w0 * h0.x + w1 * h1.x + w2 * hv2.x + w3 * h3.x;
        ay += w0 * h0.y + w1 * h1.y + w2 * hv2.y + w3 * h3.y;
    }
    for (; p < end; p++) {
        int s = srclist[p];
        float2 hv = h2[(size_t)s * 64 + l];
        float w = edge_w(a_s[s], adn);
        z += w;
        ax += w * hv.x;
        ay += w * hv.y;
    }
    float2 b = *(const float2*)&bias[2 * l];
    float ox = ax / z + b.x, oy = ay / z + b.y;
    float2 o;
    o.x = (ox > 0.f) ? ox : 0.f;
    o.y = (oy > 0.f) ? oy : 0.f;
    *(float2*)&g[(size_t)node * HD + 2 * l] = o;
}

// layer-2 aggregation fused with reduce_dim: r[n] = relu(agg+b2) . Wr + br
__global__ void k_agg2(const int* __restrict__ offsets,
                       const int* __restrict__ srclist,
                       const float* __restrict__ a_s,
                       const float* __restrict__ a_d,
                       const float2* __restrict__ h2,
                       const float* __restrict__ bias,
                       const float* __restrict__ Wr,
                       const float* __restrict__ br,
                       float* __restrict__ r) {
    int node = blockIdx.x * 4 + (threadIdx.x >> 6);
    int l = threadIdx.x & 63;
    int beg = offsets[node], end = offsets[node + 1];
    float adn = a_d[node];
    float ax = 0.f, ay = 0.f, z = 0.f;
    int p = beg;
    for (; p + 4 <= end; p += 4) {
        int s0 = srclist[p], s1 = srclist[p + 1], s2 = srclist[p + 2], s3 = srclist[p + 3];
        float2 h0 = h2[(size_t)s0 * 64 + l];
        float2 h1 = h2[(size_t)s1 * 64 + l];
        float2 hv2 = h2[(size_t)s2 * 64 + l];
        float2 h3 = h2[(size_t)s3 * 64 + l];
        float w0 = edge_w(a_s[s0], adn);
        float w1 = edge_w(a_s[s1], adn);
        float w2 = edge_w(a_s[s2], adn);
        float w3 = edge_w(a_s[s3], adn);
        z += (w0 + w1) + (w2 + w3);
        ax += w0 * h0.x + w1 * h1.x + w2 * hv2.x + w3 * h3.x;
        ay += w0 * h0.y + w1 * h1.y + w2 * hv2.y + w3 * h3.y;
    }
    for (; p < end; p++) {
        int s = srclist[p];
        float2 hv = h2[(size_t)s * 64 + l];
        float w = edge_w(a_s[s], adn);
        z += w;
        ax += w * hv.x;
        ay += w * hv.y;
    }
    float2 b = *(const float2*)&bias[2 * l];
    float ox = ax / z + b.x, oy = ay / z + b.y;
    ox = (ox > 0.f) ? ox : 0.f;
    oy = (oy > 0.f) ? oy : 0.f;
    float2 wr = *(const float2*)&Wr[2 * l];
    float part = ox * wr.x + oy * wr.y;
    #pragma unroll
    for (int off = 32; off > 0; off >>= 1) part += __shfl_down(part, off);
    if (l == 0) r[node] = part + br[0];
}

// ---------------- classifier: out[c] = sum_n r[n]*Wc[n,c] + bc[c] ----------------

__global__ void k_cls(const float* __restrict__ r,
                      const float* __restrict__ Wc,
                      const float* __restrict__ bc,
                      float* __restrict__ out) {
    __shared__ float r0[256], r1[256];
    int t = threadIdx.x;
    float c0 = 0.f, c1 = 0.f;
    for (int n = t; n < NN; n += 256) {
        float rv = r[n];
        c0 += rv * Wc[2 * n];
        c1 += rv * Wc[2 * n + 1];
    }
    r0[t] = c0; r1[t] = c1;
    __syncthreads();
    for (int off = 128; off > 0; off >>= 1) {
        if (t < off) { r0[t] += r0[t + off]; r1[t] += r1[t + off]; }
        __syncthreads();
    }
    if (t == 0) {
        out[0] = r0[0] + bc[0];
        out[1] = r1[0] + bc[1];
    }
}

// ---------------- launch ----------------

extern "C" void kernel_launch(void* const* d_in, const int* in_sizes, int n_in,
                              void* d_out, int out_size, void* d_ws, size_t ws_size,
                              hipStream_t stream) {
    const float* x    = (const float*)d_in[0];
    const int*   ei   = (const int*)d_in[1];
    const float* W1   = (const float*)d_in[2];
    const float* as1  = (const float*)d_in[3];
    const float* ad1  = (const float*)d_in[4];
    const float* b1   = (const float*)d_in[5];
    const float* W2   = (const float*)d_in[6];
    const float* as2  = (const float*)d_in[7];
    const float* ad2  = (const float*)d_in[8];
    const float* b2   = (const float*)d_in[9];
    const float* Wr   = (const float*)d_in[10];
    const float* br   = (const float*)d_in[11];
    const float* Wc   = (const float*)d_in[12];
    const float* bc   = (const float*)d_in[13];
    float* out = (float*)d_out;

    // workspace layout
    float* h    = (float*)d_ws;                  // NN*HD (16B aligned)
    float* g1   = h + (size_t)NN * HD;           // NN*HD
    float* a_s  = g1 + (size_t)NN * HD;          // NN
    float* a_d  = a_s + NN;                      // NN
    float* r    = a_d + NN;                      // NN
    int* counts  = (int*)(r + NN);               // NN
    int* offsets = counts + NN;                  // NN+1
    int* cursor  = offsets + NN + 1;             // NN
    int* srclist = cursor + NN;                  // ET

    const int TPB = 256;
    const int gET = (ET + TPB - 1) / TPB;

    // CSR build (shared by both layers)
    hipMemsetAsync(counts, 0, NN * sizeof(int), stream);
    k_hist<<<gET, TPB, 0, stream>>>(ei, counts);
    k_scan<<<1, 256, 0, stream>>>(counts, offsets, cursor);
    k_scatter<<<gET, TPB, 0, stream>>>(ei, cursor, srclist);

    // layer 1
    k_gemm1<<<NN / 16, 128, 0, stream>>>(x, W1, as1, ad1, h, a_s, a_d);
    k_agg1<<<NN / 4, 256, 0, stream>>>(offsets, srclist, a_s, a_d, (const float2*)h, b1, g1);

    // layer 2
    k_gemm2<<<NN / 16, 128, 0, stream>>>(g1, W2, as2, ad2, h, a_s, a_d);
    k_agg2<<<NN / 4, 256, 0, stream>>>(offsets, srclist, a_s, a_d, (const float2*)h, b2, Wr, br, r);

    // classifier
    k_cls<<<1, 256, 0, stream>>>(r, Wc, bc, out);
}